// Round 1
// baseline (385.175 us; speedup 1.0000x reference)
//
#include <hip/hip_runtime.h>
#include <hip/hip_bf16.h>
#include <math.h>

#define TT 2048
#define HH 2048
#define EE 8
#define II 1408

typedef short bf16x8 __attribute__((ext_vector_type(8)));
typedef float f32x4 __attribute__((ext_vector_type(4)));

__device__ __forceinline__ unsigned short f2bf(float f) {
  union { float f; unsigned int u; } v; v.f = f;
  unsigned int r = v.u + 0x7fffu + ((v.u >> 16) & 1u);
  return (unsigned short)(r >> 16);
}

// ---------------- zero out + counters ----------------
__global__ void zero_kernel(float4* __restrict__ out4, int n4, int* __restrict__ counts) {
  int i = blockIdx.x * blockDim.x + threadIdx.x;
  int stride = gridDim.x * blockDim.x;
  float4 z; z.x = 0.f; z.y = 0.f; z.z = 0.f; z.w = 0.f;
  for (; i < n4; i += stride) out4[i] = z;
  if (blockIdx.x == 0 && threadIdx.x < 2 * EE) counts[threadIdx.x] = 0; // counts + cursor (adjacent)
}

// ---------------- router: logits -> top2 -> renormalized weights ----------------
__global__ void router_kernel(const float* __restrict__ x, const float* __restrict__ gw,
                              int* __restrict__ tk_id, float* __restrict__ tk_w,
                              int* __restrict__ counts) {
  int t = blockIdx.x;
  int lane = threadIdx.x;
  float acc[EE];
#pragma unroll
  for (int e = 0; e < EE; ++e) acc[e] = 0.f;
  const float* xr = x + (size_t)t * HH;
  for (int h = lane; h < HH; h += 64) {
    float xv = xr[h];
    const float* g = gw + (size_t)h * EE;
#pragma unroll
    for (int e = 0; e < EE; ++e) acc[e] += xv * g[e];
  }
#pragma unroll
  for (int off = 32; off > 0; off >>= 1) {
#pragma unroll
    for (int e = 0; e < EE; ++e) acc[e] += __shfl_down(acc[e], off, 64);
  }
  if (lane == 0) {
    int i0 = 0;
#pragma unroll
    for (int e = 1; e < EE; ++e) if (acc[e] > acc[i0]) i0 = e;
    int i1 = (i0 == 0) ? 1 : 0;
#pragma unroll
    for (int e = 0; e < EE; ++e) { if (e == i0) continue; if (acc[e] > acc[i1]) i1 = e; }
    // softmax over all 8 then renorm over top-2 == 2-way softmax of the two logits
    float d = acc[i1] - acc[i0];     // <= 0
    float p1 = expf(d);
    float w0 = 1.f / (1.f + p1);
    float w1v = p1 * w0;
    tk_id[2 * t] = i0; tk_id[2 * t + 1] = i1;
    tk_w[2 * t] = w0;  tk_w[2 * t + 1] = w1v;
    atomicAdd(&counts[i0], 1);
    atomicAdd(&counts[i1], 1);
  }
}

// ---------------- scan: offsets from counts, reset cursors ----------------
__global__ void scan_kernel(const int* __restrict__ counts, int* __restrict__ offsets,
                            int* __restrict__ cursor) {
  if (threadIdx.x == 0) {
    int s = 0;
    for (int e = 0; e < EE; ++e) { offsets[e] = s; s += counts[e]; cursor[e] = 0; }
    offsets[EE] = s;   // == 2*TT
  }
}

// ---------------- assign: build per-expert token lists ----------------
__global__ void assign_kernel(const int* __restrict__ tk_id, const float* __restrict__ tk_w,
                              const int* __restrict__ offsets, int* __restrict__ cursor,
                              int* __restrict__ tok_list, float* __restrict__ wt_list) {
  int t = blockIdx.x * blockDim.x + threadIdx.x;
  if (t >= TT) return;
#pragma unroll
  for (int k = 0; k < 2; ++k) {
    int e = tk_id[2 * t + k];
    int p = atomicAdd(&cursor[e], 1);
    int slot = offsets[e] + p;
    tok_list[slot] = t;
    wt_list[slot] = tk_w[2 * t + k];
  }
}

// ---------------- GEMM1: mid = silu(gather(x) @ w1[e]) -> bf16 ----------------
__launch_bounds__(256, 2)
__global__ void gemm1_kernel(const float* __restrict__ x, const float* __restrict__ w1,
                             const int* __restrict__ tok_list, const int* __restrict__ offsets,
                             unsigned short* __restrict__ mid) {
  int e = blockIdx.z;
  int g_off = offsets[e];
  int n_e = offsets[e + 1] - g_off;
  int row0 = blockIdx.y * 64;
  if (row0 >= n_e) return;
  int n0 = blockIdx.x * 64;

  __shared__ unsigned short sA[64][72];
  __shared__ unsigned short sB[64][72];   // transposed: sB[n][k]
  __shared__ int s_tok[64];

  int tid = threadIdx.x;
  if (tid < 64) {
    int r = row0 + tid;
    s_tok[tid] = tok_list[g_off + ((r < n_e) ? r : (n_e - 1))];
  }
  __syncthreads();

  int lane = tid & 63;
  int wv = tid >> 6;
  int wm = wv >> 1, wn = wv & 1;
  int fr = lane & 15, kg = lane >> 4;

  f32x4 acc[2][2];
#pragma unroll
  for (int i = 0; i < 2; ++i)
#pragma unroll
    for (int j = 0; j < 2; ++j)
      acc[i][j] = (f32x4){0.f, 0.f, 0.f, 0.f};

  const float* w1e = w1 + (size_t)e * HH * II;

  for (int k0 = 0; k0 < HH; k0 += 64) {
    // stage A: gathered x rows, fp32 -> bf16
#pragma unroll
    for (int i = 0; i < 4; ++i) {
      int idx = tid + i * 256;
      int r = idx >> 4, c4 = idx & 15;
      float4 v = *(const float4*)(x + (size_t)s_tok[r] * HH + k0 + c4 * 4);
      unsigned long long pk = (unsigned long long)f2bf(v.x)
                            | ((unsigned long long)f2bf(v.y) << 16)
                            | ((unsigned long long)f2bf(v.z) << 32)
                            | ((unsigned long long)f2bf(v.w) << 48);
      *(unsigned long long*)(&sA[r][c4 * 4]) = pk;
    }
    // stage B transposed: w1[e][k][n] -> sB[n][k]
#pragma unroll
    for (int i = 0; i < 4; ++i) {
      int idx = tid + i * 256;
      int kk = idx >> 4, c4 = idx & 15;
      float4 v = *(const float4*)(w1e + (size_t)(k0 + kk) * II + n0 + c4 * 4);
      sB[c4 * 4 + 0][kk] = f2bf(v.x);
      sB[c4 * 4 + 1][kk] = f2bf(v.y);
      sB[c4 * 4 + 2][kk] = f2bf(v.z);
      sB[c4 * 4 + 3][kk] = f2bf(v.w);
    }
    __syncthreads();
#pragma unroll
    for (int kk = 0; kk < 64; kk += 32) {
      bf16x8 af[2], bg[2];
#pragma unroll
      for (int m = 0; m < 2; ++m)
        af[m] = *(const bf16x8*)(&sA[wm * 32 + m * 16 + fr][kk + kg * 8]);
#pragma unroll
      for (int n = 0; n < 2; ++n)
        bg[n] = *(const bf16x8*)(&sB[wn * 32 + n * 16 + fr][kk + kg * 8]);
#pragma unroll
      for (int m = 0; m < 2; ++m)
#pragma unroll
        for (int n = 0; n < 2; ++n)
          acc[m][n] = __builtin_amdgcn_mfma_f32_16x16x32_bf16(af[m], bg[n], acc[m][n], 0, 0, 0);
    }
    __syncthreads();
  }

  // epilogue: silu, store mid as bf16
#pragma unroll
  for (int m = 0; m < 2; ++m) {
#pragma unroll
    for (int n = 0; n < 2; ++n) {
#pragma unroll
      for (int r = 0; r < 4; ++r) {
        int lr = wm * 32 + m * 16 + kg * 4 + r;
        int lc = wn * 32 + n * 16 + fr;
        if (row0 + lr < n_e) {
          float v = acc[m][n][r];
          float s = v / (1.f + expf(-v));
          mid[(size_t)(g_off + row0 + lr) * II + n0 + lc] = f2bf(s);
        }
      }
    }
  }
}

// ---------------- GEMM2: out += wt * (mid @ w2[e]) ----------------
__launch_bounds__(256, 2)
__global__ void gemm2_kernel(const unsigned short* __restrict__ mid, const float* __restrict__ w2,
                             const int* __restrict__ tok_list, const float* __restrict__ wt_list,
                             const int* __restrict__ offsets, float* __restrict__ out) {
  int e = blockIdx.z;
  int g_off = offsets[e];
  int n_e = offsets[e + 1] - g_off;
  int row0 = blockIdx.y * 64;
  if (row0 >= n_e) return;
  int n0 = blockIdx.x * 64;

  __shared__ unsigned short sA[64][72];
  __shared__ unsigned short sB[64][72];   // transposed: sB[n][k]
  __shared__ int s_tok[64];
  __shared__ float s_wt[64];

  int tid = threadIdx.x;
  if (tid < 64) {
    int r = row0 + tid;
    int cr = (r < n_e) ? r : (n_e - 1);
    s_tok[tid] = tok_list[g_off + cr];
    s_wt[tid] = wt_list[g_off + cr];
  }
  __syncthreads();

  int lane = tid & 63;
  int wv = tid >> 6;
  int wm = wv >> 1, wn = wv & 1;
  int fr = lane & 15, kg = lane >> 4;

  f32x4 acc[2][2];
#pragma unroll
  for (int i = 0; i < 2; ++i)
#pragma unroll
    for (int j = 0; j < 2; ++j)
      acc[i][j] = (f32x4){0.f, 0.f, 0.f, 0.f};

  const float* w2e = w2 + (size_t)e * II * HH;

  for (int k0 = 0; k0 < II; k0 += 64) {
    // stage A from mid (already bf16)
#pragma unroll
    for (int i = 0; i < 2; ++i) {
      int idx = tid + i * 256;          // 0..511
      int r = idx >> 3, c8 = idx & 7;
      int gr = row0 + r; if (gr >= n_e) gr = n_e - 1;
      uint4 v = *(const uint4*)(mid + (size_t)(g_off + gr) * II + k0 + c8 * 8);
      *(uint4*)(&sA[r][c8 * 8]) = v;
    }
    // stage B transposed: w2[e][k][n] -> sB[n][k]
#pragma unroll
    for (int i = 0; i < 4; ++i) {
      int idx = tid + i * 256;
      int kk = idx >> 4, c4 = idx & 15;
      float4 v = *(const float4*)(w2e + (size_t)(k0 + kk) * HH + n0 + c4 * 4);
      sB[c4 * 4 + 0][kk] = f2bf(v.x);
      sB[c4 * 4 + 1][kk] = f2bf(v.y);
      sB[c4 * 4 + 2][kk] = f2bf(v.z);
      sB[c4 * 4 + 3][kk] = f2bf(v.w);
    }
    __syncthreads();
#pragma unroll
    for (int kk = 0; kk < 64; kk += 32) {
      bf16x8 af[2], bg[2];
#pragma unroll
      for (int m = 0; m < 2; ++m)
        af[m] = *(const bf16x8*)(&sA[wm * 32 + m * 16 + fr][kk + kg * 8]);
#pragma unroll
      for (int n = 0; n < 2; ++n)
        bg[n] = *(const bf16x8*)(&sB[wn * 32 + n * 16 + fr][kk + kg * 8]);
#pragma unroll
      for (int m = 0; m < 2; ++m)
#pragma unroll
        for (int n = 0; n < 2; ++n)
          acc[m][n] = __builtin_amdgcn_mfma_f32_16x16x32_bf16(af[m], bg[n], acc[m][n], 0, 0, 0);
    }
    __syncthreads();
  }

  // epilogue: scale by routing weight, scatter-accumulate into out
#pragma unroll
  for (int m = 0; m < 2; ++m) {
#pragma unroll
    for (int n = 0; n < 2; ++n) {
#pragma unroll
      for (int r = 0; r < 4; ++r) {
        int lr = wm * 32 + m * 16 + kg * 4 + r;
        int lc = wn * 32 + n * 16 + fr;
        if (row0 + lr < n_e) {
          float v = acc[m][n][r] * s_wt[lr];
          atomicAdd(out + (size_t)s_tok[lr] * HH + n0 + lc, v);
        }
      }
    }
  }
}

extern "C" void kernel_launch(void* const* d_in, const int* in_sizes, int n_in,
                              void* d_out, int out_size, void* d_ws, size_t ws_size,
                              hipStream_t stream) {
  const float* x  = (const float*)d_in[0];
  const float* gw = (const float*)d_in[1];
  const float* w1 = (const float*)d_in[2];
  const float* w2 = (const float*)d_in[3];
  float* out = (float*)d_out;

  char* ws = (char*)d_ws;
  int*   tk_id    = (int*)(ws);                 // 4096 ints
  float* tk_w     = (float*)(ws + 16384);       // 4096 floats
  int*   counts   = (int*)(ws + 32768);         // 8
  int*   cursor   = (int*)(ws + 32800);         // 8 (adjacent to counts)
  int*   offsets  = (int*)(ws + 32832);         // 9
  int*   tok_list = (int*)(ws + 32896);         // 4096
  float* wt_list  = (float*)(ws + 49280);       // 4096
  unsigned short* mid = (unsigned short*)(ws + 131072);  // [4096][1408] bf16

  zero_kernel<<<1024, 256, 0, stream>>>((float4*)out, TT * HH / 4, counts);
  router_kernel<<<TT, 64, 0, stream>>>(x, gw, tk_id, tk_w, counts);
  scan_kernel<<<1, 64, 0, stream>>>(counts, offsets, cursor);
  assign_kernel<<<TT / 256, 256, 0, stream>>>(tk_id, tk_w, offsets, cursor, tok_list, wt_list);
  gemm1_kernel<<<dim3(II / 64, TT / 64, EE), 256, 0, stream>>>(x, w1, tok_list, offsets, mid);
  gemm2_kernel<<<dim3(HH / 64, TT / 64, EE), 256, 0, stream>>>(mid, w2, tok_list, wt_list, offsets, out);
}

// Round 2
// 292.405 us; speedup vs baseline: 1.3173x; 1.3173x over previous
//
#include <hip/hip_runtime.h>
#include <hip/hip_bf16.h>
#include <math.h>

#define TT 2048
#define HH 2048
#define EE 8
#define II 1408

typedef short bf16x8 __attribute__((ext_vector_type(8)));
typedef float f32x4 __attribute__((ext_vector_type(4)));
typedef unsigned int u32;
typedef unsigned short u16;

__device__ __forceinline__ u16 f2bf(float f) {
  union { float f; u32 u; } v; v.f = f;
  u32 r = v.u + 0x7fffu + ((v.u >> 16) & 1u);
  return (u16)(r >> 16);
}

__device__ __forceinline__ void gload16(const void* g, void* l) {
  __builtin_amdgcn_global_load_lds((const __attribute__((address_space(1))) u32*)g,
                                   (__attribute__((address_space(3))) u32*)l, 16, 0, 0);
}

// ---------------- zero out + counters ----------------
__global__ void zero_kernel(float4* __restrict__ out4, int n4, int* __restrict__ counts) {
  int i = blockIdx.x * blockDim.x + threadIdx.x;
  int stride = gridDim.x * blockDim.x;
  float4 z; z.x = 0.f; z.y = 0.f; z.z = 0.f; z.w = 0.f;
  for (; i < n4; i += stride) out4[i] = z;
  if (blockIdx.x == 0 && threadIdx.x < 2 * EE) counts[threadIdx.x] = 0;
}

// ---------------- router ----------------
__global__ void router_kernel(const float* __restrict__ x, const float* __restrict__ gw,
                              int* __restrict__ tk_id, float* __restrict__ tk_w,
                              int* __restrict__ counts) {
  int t = blockIdx.x;
  int lane = threadIdx.x;
  float acc[EE];
#pragma unroll
  for (int e = 0; e < EE; ++e) acc[e] = 0.f;
  const float* xr = x + (size_t)t * HH;
  for (int h = lane; h < HH; h += 64) {
    float xv = xr[h];
    const float* g = gw + (size_t)h * EE;
#pragma unroll
    for (int e = 0; e < EE; ++e) acc[e] += xv * g[e];
  }
#pragma unroll
  for (int off = 32; off > 0; off >>= 1) {
#pragma unroll
    for (int e = 0; e < EE; ++e) acc[e] += __shfl_down(acc[e], off, 64);
  }
  if (lane == 0) {
    int i0 = 0;
#pragma unroll
    for (int e = 1; e < EE; ++e) if (acc[e] > acc[i0]) i0 = e;
    int i1 = (i0 == 0) ? 1 : 0;
#pragma unroll
    for (int e = 0; e < EE; ++e) { if (e == i0) continue; if (acc[e] > acc[i1]) i1 = e; }
    float d = acc[i1] - acc[i0];
    float p1 = expf(d);
    float w0 = 1.f / (1.f + p1);
    float w1v = p1 * w0;
    tk_id[2 * t] = i0; tk_id[2 * t + 1] = i1;
    tk_w[2 * t] = w0;  tk_w[2 * t + 1] = w1v;
    atomicAdd(&counts[i0], 1);
    atomicAdd(&counts[i1], 1);
  }
}

// ---------------- scan ----------------
__global__ void scan_kernel(const int* __restrict__ counts, int* __restrict__ offsets,
                            int* __restrict__ cursor) {
  if (threadIdx.x == 0) {
    int s = 0;
    for (int e = 0; e < EE; ++e) { offsets[e] = s; s += counts[e]; cursor[e] = 0; }
    offsets[EE] = s;
  }
}

// ---------------- assign ----------------
__global__ void assign_kernel(const int* __restrict__ tk_id, const float* __restrict__ tk_w,
                              const int* __restrict__ offsets, int* __restrict__ cursor,
                              int* __restrict__ tok_list, float* __restrict__ wt_list) {
  int t = blockIdx.x * blockDim.x + threadIdx.x;
  if (t >= TT) return;
#pragma unroll
  for (int k = 0; k < 2; ++k) {
    int e = tk_id[2 * t + k];
    int p = atomicAdd(&cursor[e], 1);
    int slot = offsets[e] + p;
    tok_list[slot] = t;
    wt_list[slot] = tk_w[2 * t + k];
  }
}

// ---------------- gather x -> bf16 xg[slot][H] ----------------
__global__ void gather_x_kernel(const float* __restrict__ x, const int* __restrict__ tok_list,
                                u16* __restrict__ xg) {
  int slot = blockIdx.x;
  int tok = tok_list[slot];
  int c = threadIdx.x * 8;
  float4 v0 = *(const float4*)(x + (size_t)tok * HH + c);
  float4 v1 = *(const float4*)(x + (size_t)tok * HH + c + 4);
  u16 o[8] = { f2bf(v0.x), f2bf(v0.y), f2bf(v0.z), f2bf(v0.w),
               f2bf(v1.x), f2bf(v1.y), f2bf(v1.z), f2bf(v1.w) };
  *(uint4*)(xg + (size_t)slot * HH + c) = *(uint4*)o;
}

// ---------------- convert + transpose: w[e][K][N] fp32 -> wb[e][N][K] bf16 ----------------
__global__ void convtrans_kernel(const float* __restrict__ w, u16* __restrict__ wb,
                                 int K, int N) {
  int e = blockIdx.z;
  int n0 = blockIdx.x * 64, k0 = blockIdx.y * 64;
  __shared__ u16 sT[64][72];
  const float* we = w + (size_t)e * K * N;
  u16* wbe = wb + (size_t)e * K * N;
  int tid = threadIdx.x;
  int kl = tid >> 4, n4 = tid & 15;
#pragma unroll
  for (int j = 0; j < 4; ++j) {
    int k = kl + j * 16;
    float4 v = *(const float4*)(we + (size_t)(k0 + k) * N + n0 + n4 * 4);
    sT[n4 * 4 + 0][k] = f2bf(v.x);
    sT[n4 * 4 + 1][k] = f2bf(v.y);
    sT[n4 * 4 + 2][k] = f2bf(v.z);
    sT[n4 * 4 + 3][k] = f2bf(v.w);
  }
  __syncthreads();
  int nl = tid >> 3, kc = tid & 7;
#pragma unroll
  for (int j = 0; j < 2; ++j) {
    int n = nl + j * 32;
    uint4 v = *(const uint4*)(&sT[n][kc * 8]);
    *(uint4*)(wbe + (size_t)(n0 + n) * K + k0 + kc * 8) = v;
  }
}

// ---------------- grouped GEMM, 128x128x64, gload_lds + XOR swizzle ----------------
// A: [slot][KDIM] bf16 (contiguous slots, padded with slack rows)
// B: [e][Ndim][KDIM] bf16 (N-major)
template <int KDIM, bool G2>
__launch_bounds__(256)
__global__ void moe_gemm_kernel(const u16* __restrict__ A, const u16* __restrict__ B,
                                const int* __restrict__ tok_list,
                                const float* __restrict__ wt_list,
                                const int* __restrict__ offsets,
                                u16* __restrict__ mid, float* __restrict__ out) {
  int e = blockIdx.z;
  int g_off = offsets[e];
  int n_e = offsets[e + 1] - g_off;
  int row0 = blockIdx.y * 128;
  if (row0 >= n_e) return;
  int n0 = blockIdx.x * 128;

  __shared__ u16 sA[128][64];
  __shared__ u16 sB[128][64];
  __shared__ int s_tok[128];
  __shared__ float s_wt[128];

  int tid = threadIdx.x;
  int lane = tid & 63, wv = tid >> 6;
  int wm = wv >> 1, wn = wv & 1;
  int fr = lane & 15, kg = lane >> 4;

  if constexpr (G2) {
    if (tid < 128) {
      int r = row0 + tid;
      int cr = r < n_e ? r : n_e - 1;
      s_tok[tid] = tok_list[g_off + cr];
      s_wt[tid] = wt_list[g_off + cr];
    }
  }

  // staging: lane l covers 16B at LDS chunk-offset l*16; chunk c = j*4 + wv covers rows c*8..+7.
  // source col is pre-swizzled (XOR involution) so swizzled ds_read sees correct data.
  int rA = lane >> 3;                           // row within 8-row chunk
  int colsw = ((lane & 7) ^ rA) * 8;            // pre-swizzled col (elems)
  const int Ndim = G2 ? HH : II;
  const u16* Abase = A + (size_t)(g_off + row0 + rA) * KDIM + colsw;
  const u16* Bbase = B + (size_t)e * (size_t)Ndim * KDIM + (size_t)(n0 + rA) * KDIM + colsw;

  f32x4 acc[4][4];
#pragma unroll
  for (int m = 0; m < 4; ++m)
#pragma unroll
    for (int n = 0; n < 4; ++n)
      acc[m][n] = (f32x4){0.f, 0.f, 0.f, 0.f};

  for (int k0 = 0; k0 < KDIM; k0 += 64) {
#pragma unroll
    for (int j = 0; j < 4; ++j) {
      int c = j * 4 + wv;
      gload16(Abase + (size_t)c * 8 * KDIM + k0, &sA[c * 8][0]);
      gload16(Bbase + (size_t)c * 8 * KDIM + k0, &sB[c * 8][0]);
    }
    __syncthreads();
#pragma unroll
    for (int kh = 0; kh < 2; ++kh) {
      bf16x8 af[4], bg[4];
      int cb = (kh * 64 + kg * 16) ^ ((fr & 7) << 4);
#pragma unroll
      for (int m = 0; m < 4; ++m) {
        int row = wm * 64 + m * 16 + fr;
        af[m] = *(const bf16x8*)((const char*)&sA[0][0] + row * 128 + cb);
      }
#pragma unroll
      for (int n = 0; n < 4; ++n) {
        int row = wn * 64 + n * 16 + fr;
        bg[n] = *(const bf16x8*)((const char*)&sB[0][0] + row * 128 + cb);
      }
#pragma unroll
      for (int m = 0; m < 4; ++m)
#pragma unroll
        for (int n = 0; n < 4; ++n)
          acc[m][n] = __builtin_amdgcn_mfma_f32_16x16x32_bf16(af[m], bg[n], acc[m][n], 0, 0, 0);
    }
    __syncthreads();
  }

#pragma unroll
  for (int m = 0; m < 4; ++m) {
    int lr = wm * 64 + m * 16 + kg * 4;
#pragma unroll
    for (int n = 0; n < 4; ++n) {
      int lc = wn * 64 + n * 16 + fr;
#pragma unroll
      for (int r = 0; r < 4; ++r) {
        int rr = lr + r;
        if (row0 + rr < n_e) {
          if constexpr (G2) {
            float v = acc[m][n][r] * s_wt[rr];
            atomicAdd(out + (size_t)s_tok[rr] * HH + n0 + lc, v);
          } else {
            float v = acc[m][n][r];
            float s = v / (1.f + expf(-v));
            mid[(size_t)(g_off + row0 + rr) * II + n0 + lc] = f2bf(s);
          }
        }
      }
    }
  }
}

// ================= FALLBACK (round-1, proven) =================
__launch_bounds__(256, 2)
__global__ void gemm1_small(const float* __restrict__ x, const float* __restrict__ w1,
                            const int* __restrict__ tok_list, const int* __restrict__ offsets,
                            u16* __restrict__ mid) {
  int e = blockIdx.z;
  int g_off = offsets[e];
  int n_e = offsets[e + 1] - g_off;
  int row0 = blockIdx.y * 64;
  if (row0 >= n_e) return;
  int n0 = blockIdx.x * 64;
  __shared__ u16 sA[64][72];
  __shared__ u16 sB[64][72];
  __shared__ int s_tok[64];
  int tid = threadIdx.x;
  if (tid < 64) {
    int r = row0 + tid;
    s_tok[tid] = tok_list[g_off + ((r < n_e) ? r : (n_e - 1))];
  }
  __syncthreads();
  int lane = tid & 63;
  int wv = tid >> 6;
  int wm = wv >> 1, wn = wv & 1;
  int fr = lane & 15, kg = lane >> 4;
  f32x4 acc[2][2];
#pragma unroll
  for (int i = 0; i < 2; ++i)
#pragma unroll
    for (int j = 0; j < 2; ++j) acc[i][j] = (f32x4){0.f, 0.f, 0.f, 0.f};
  const float* w1e = w1 + (size_t)e * HH * II;
  for (int k0 = 0; k0 < HH; k0 += 64) {
#pragma unroll
    for (int i = 0; i < 4; ++i) {
      int idx = tid + i * 256;
      int r = idx >> 4, c4 = idx & 15;
      float4 v = *(const float4*)(x + (size_t)s_tok[r] * HH + k0 + c4 * 4);
      unsigned long long pk = (unsigned long long)f2bf(v.x)
                            | ((unsigned long long)f2bf(v.y) << 16)
                            | ((unsigned long long)f2bf(v.z) << 32)
                            | ((unsigned long long)f2bf(v.w) << 48);
      *(unsigned long long*)(&sA[r][c4 * 4]) = pk;
    }
#pragma unroll
    for (int i = 0; i < 4; ++i) {
      int idx = tid + i * 256;
      int kk = idx >> 4, c4 = idx & 15;
      float4 v = *(const float4*)(w1e + (size_t)(k0 + kk) * II + n0 + c4 * 4);
      sB[c4 * 4 + 0][kk] = f2bf(v.x);
      sB[c4 * 4 + 1][kk] = f2bf(v.y);
      sB[c4 * 4 + 2][kk] = f2bf(v.z);
      sB[c4 * 4 + 3][kk] = f2bf(v.w);
    }
    __syncthreads();
#pragma unroll
    for (int kk = 0; kk < 64; kk += 32) {
      bf16x8 af[2], bg[2];
#pragma unroll
      for (int m = 0; m < 2; ++m) af[m] = *(const bf16x8*)(&sA[wm * 32 + m * 16 + fr][kk + kg * 8]);
#pragma unroll
      for (int n = 0; n < 2; ++n) bg[n] = *(const bf16x8*)(&sB[wn * 32 + n * 16 + fr][kk + kg * 8]);
#pragma unroll
      for (int m = 0; m < 2; ++m)
#pragma unroll
        for (int n = 0; n < 2; ++n)
          acc[m][n] = __builtin_amdgcn_mfma_f32_16x16x32_bf16(af[m], bg[n], acc[m][n], 0, 0, 0);
    }
    __syncthreads();
  }
#pragma unroll
  for (int m = 0; m < 2; ++m)
#pragma unroll
    for (int n = 0; n < 2; ++n)
#pragma unroll
      for (int r = 0; r < 4; ++r) {
        int lr = wm * 32 + m * 16 + kg * 4 + r;
        int lc = wn * 32 + n * 16 + fr;
        if (row0 + lr < n_e) {
          float v = acc[m][n][r];
          float s = v / (1.f + expf(-v));
          mid[(size_t)(g_off + row0 + lr) * II + n0 + lc] = f2bf(s);
        }
      }
}

__launch_bounds__(256, 2)
__global__ void gemm2_small(const u16* __restrict__ mid, const float* __restrict__ w2,
                            const int* __restrict__ tok_list, const float* __restrict__ wt_list,
                            const int* __restrict__ offsets, float* __restrict__ out) {
  int e = blockIdx.z;
  int g_off = offsets[e];
  int n_e = offsets[e + 1] - g_off;
  int row0 = blockIdx.y * 64;
  if (row0 >= n_e) return;
  int n0 = blockIdx.x * 64;
  __shared__ u16 sA[64][72];
  __shared__ u16 sB[64][72];
  __shared__ int s_tok[64];
  __shared__ float s_wt[64];
  int tid = threadIdx.x;
  if (tid < 64) {
    int r = row0 + tid;
    int cr = (r < n_e) ? r : (n_e - 1);
    s_tok[tid] = tok_list[g_off + cr];
    s_wt[tid] = wt_list[g_off + cr];
  }
  __syncthreads();
  int lane = tid & 63;
  int wv = tid >> 6;
  int wm = wv >> 1, wn = wv & 1;
  int fr = lane & 15, kg = lane >> 4;
  f32x4 acc[2][2];
#pragma unroll
  for (int i = 0; i < 2; ++i)
#pragma unroll
    for (int j = 0; j < 2; ++j) acc[i][j] = (f32x4){0.f, 0.f, 0.f, 0.f};
  const float* w2e = w2 + (size_t)e * II * HH;
  for (int k0 = 0; k0 < II; k0 += 64) {
#pragma unroll
    for (int i = 0; i < 2; ++i) {
      int idx = tid + i * 256;
      int r = idx >> 3, c8 = idx & 7;
      int gr = row0 + r; if (gr >= n_e) gr = n_e - 1;
      uint4 v = *(const uint4*)(mid + (size_t)(g_off + gr) * II + k0 + c8 * 8);
      *(uint4*)(&sA[r][c8 * 8]) = v;
    }
#pragma unroll
    for (int i = 0; i < 4; ++i) {
      int idx = tid + i * 256;
      int kk = idx >> 4, c4 = idx & 15;
      float4 v = *(const float4*)(w2e + (size_t)(k0 + kk) * HH + n0 + c4 * 4);
      sB[c4 * 4 + 0][kk] = f2bf(v.x);
      sB[c4 * 4 + 1][kk] = f2bf(v.y);
      sB[c4 * 4 + 2][kk] = f2bf(v.z);
      sB[c4 * 4 + 3][kk] = f2bf(v.w);
    }
    __syncthreads();
#pragma unroll
    for (int kk = 0; kk < 64; kk += 32) {
      bf16x8 af[2], bg[2];
#pragma unroll
      for (int m = 0; m < 2; ++m) af[m] = *(const bf16x8*)(&sA[wm * 32 + m * 16 + fr][kk + kg * 8]);
#pragma unroll
      for (int n = 0; n < 2; ++n) bg[n] = *(const bf16x8*)(&sB[wn * 32 + n * 16 + fr][kk + kg * 8]);
#pragma unroll
      for (int m = 0; m < 2; ++m)
#pragma unroll
        for (int n = 0; n < 2; ++n)
          acc[m][n] = __builtin_amdgcn_mfma_f32_16x16x32_bf16(af[m], bg[n], acc[m][n], 0, 0, 0);
    }
    __syncthreads();
  }
#pragma unroll
  for (int m = 0; m < 2; ++m)
#pragma unroll
    for (int n = 0; n < 2; ++n)
#pragma unroll
      for (int r = 0; r < 4; ++r) {
        int lr = wm * 32 + m * 16 + kg * 4 + r;
        int lc = wn * 32 + n * 16 + fr;
        if (row0 + lr < n_e) {
          float v = acc[m][n][r] * s_wt[lr];
          atomicAdd(out + (size_t)s_tok[lr] * HH + n0 + lc, v);
        }
      }
}

extern "C" void kernel_launch(void* const* d_in, const int* in_sizes, int n_in,
                              void* d_out, int out_size, void* d_ws, size_t ws_size,
                              hipStream_t stream) {
  const float* x  = (const float*)d_in[0];
  const float* gw = (const float*)d_in[1];
  const float* w1 = (const float*)d_in[2];
  const float* w2 = (const float*)d_in[3];
  float* out = (float*)d_out;

  char* ws = (char*)d_ws;
  int*   tk_id    = (int*)(ws);
  float* tk_w     = (float*)(ws + 16384);
  int*   counts   = (int*)(ws + 32768);
  int*   cursor   = (int*)(ws + 32800);
  int*   offsets  = (int*)(ws + 32832);
  int*   tok_list = (int*)(ws + 33024);
  float* wt_list  = (float*)(ws + 49408);

  // fast-path layout
  u16* xg  = (u16*)(ws + (1u << 20));                       // [4224][2048] bf16
  u16* midB = (u16*)(ws + (20u << 20));                     // [4224][1408] bf16
  u16* w1b = (u16*)(ws + (33u << 20));                      // [8][1408][2048] bf16
  u16* w2b = (u16*)(ws + 80740352u);                        // [8][2048][1408] bf16
  const size_t NEED = 80740352u + (size_t)EE * HH * II * 2; // 126,877,696

  zero_kernel<<<1024, 256, 0, stream>>>((float4*)out, TT * HH / 4, counts);
  router_kernel<<<TT, 64, 0, stream>>>(x, gw, tk_id, tk_w, counts);
  scan_kernel<<<1, 64, 0, stream>>>(counts, offsets, cursor);
  assign_kernel<<<TT / 256, 256, 0, stream>>>(tk_id, tk_w, offsets, cursor, tok_list, wt_list);

  if (ws_size >= NEED) {
    gather_x_kernel<<<2 * TT, 256, 0, stream>>>(x, tok_list, xg);
    convtrans_kernel<<<dim3(II / 64, HH / 64, EE), 256, 0, stream>>>(w1, w1b, HH, II);
    convtrans_kernel<<<dim3(HH / 64, II / 64, EE), 256, 0, stream>>>(w2, w2b, II, HH);
    moe_gemm_kernel<HH, false><<<dim3(II / 128, 32, EE), 256, 0, stream>>>(
        xg, w1b, tok_list, wt_list, offsets, midB, out);
    moe_gemm_kernel<II, true><<<dim3(HH / 128, 32, EE), 256, 0, stream>>>(
        midB, w2b, tok_list, wt_list, offsets, midB, out);
  } else {
    u16* mid0 = (u16*)(ws + 131072);
    gemm1_small<<<dim3(II / 64, TT / 64, EE), 256, 0, stream>>>(x, w1, tok_list, offsets, mid0);
    gemm2_small<<<dim3(HH / 64, TT / 64, EE), 256, 0, stream>>>(mid0, w2, tok_list, wt_list, offsets, out);
  }
}